// Round 5
// baseline (125.250 us; speedup 1.0000x reference)
//
#include <hip/hip_runtime.h>
#include <math.h>

#define N_INW     1024
#define N_DEPTH   8
#define N_GROW    512
#define N_BATCH   4096
#define N_ROWS    4608   // IN_W + 7*GROW — rows ever read/written before the output
#define N_COL     4      // batch columns per workgroup (73728 B LDS -> 2 WGs/CU)
#define N_THREADS 256    // 64 butterfly blocks * 4 cols
#define N_LAYERS  64

typedef __attribute__((ext_vector_type(2))) float F2;

struct CS { float4 c0, c1, s0, s1; };   // c[0..7], s[0..7] for one (module,layer,blk)

// cs table planes: layer g: cos plane at [(2g)*512 + p], sin plane at [(2g+1)*512 + p]
__global__ void precompute_cs_kernel(const float* __restrict__ angles,
                                     float* __restrict__ cs) {
    int i = blockIdx.x * blockDim.x + threadIdx.x;
    if (i < N_LAYERS * 512) {
        int g = i >> 9, p = i & 511;
        float a = angles[i];
        cs[(2 * g) * 512 + p]     = cosf(a);
        cs[(2 * g + 1) * 512 + p] = sinf(a);
    }
}

__device__ __forceinline__ F2 f2mk(float a, float b) { F2 r; r.x = a; r.y = b; return r; }
__device__ __forceinline__ F2 flo(float4 v) { return f2mk(v.x, v.y); }
__device__ __forceinline__ F2 fhi(float4 v) { return f2mk(v.z, v.w); }

template <bool USE_TABLE>
__device__ __forceinline__ CS load_cs(const float* __restrict__ tab,
                                      const float* __restrict__ angles,
                                      int g, int blk) {
    CS r;
    if (USE_TABLE) {
        const float4* c = (const float4*)(tab + (2 * g) * 512 + blk * 8);
        const float4* s = (const float4*)(tab + (2 * g + 1) * 512 + blk * 8);
        r.c0 = c[0]; r.c1 = c[1]; r.s0 = s[0]; r.s1 = s[1];
    } else {
        const float4* p = (const float4*)(angles + g * 512 + blk * 8);
        float4 a0 = p[0], a1 = p[1];
        float av[8] = {a0.x, a0.y, a0.z, a0.w, a1.x, a1.y, a1.z, a1.w};
        float c[8], s[8];
#pragma unroll
        for (int q = 0; q < 8; ++q) __sincosf(av[q], &s[q], &c[q]);
        r.c0 = make_float4(c[0], c[1], c[2], c[3]);
        r.c1 = make_float4(c[4], c[5], c[6], c[7]);
        r.s0 = make_float4(s[0], s[1], s[2], s[3]);
        r.s1 = make_float4(s[4], s[5], s[6], s[7]);
    }
    return r;
}

// LDS swizzle: element (row r, col c) -> r*4 + ((c + (r>>3)) & 3). Makes the
// act-append conflict-free in NATURAL j order (swizzle class varies with blk),
// so no runtime-indexed private arrays are needed anywhere.
__device__ __forceinline__ int lds_addr(int r, int c) {
    return (r * 4 + ((c + (r >> 3)) & 3)) * 4;
}

// ---- rotation layers; xv[k] = (x[2k], x[2k+1]); S>=2 are pure packed fp32 ----
__device__ __forceinline__ void rot1(F2 xv[8], const CS& C) {
    float cc[8] = {C.c0.x, C.c0.y, C.c0.z, C.c0.w, C.c1.x, C.c1.y, C.c1.z, C.c1.w};
    float ss[8] = {C.s0.x, C.s0.y, C.s0.z, C.s0.w, C.s1.x, C.s1.y, C.s1.z, C.s1.w};
#pragma unroll
    for (int k = 0; k < 8; ++k) {
        float lo = xv[k].x, hi = xv[k].y;
        xv[k].x = cc[k] * lo + ss[k] * hi;
        xv[k].y = cc[k] * hi - ss[k] * lo;
    }
}
__device__ __forceinline__ void rot2(F2 xv[8], const CS& C) {
    F2 cf[4] = {flo(C.c0), fhi(C.c0), flo(C.c1), fhi(C.c1)};
    F2 sf[4] = {flo(C.s0), fhi(C.s0), flo(C.s1), fhi(C.s1)};
#pragma unroll
    for (int k = 0; k < 4; ++k) {
        F2 lo = xv[2 * k], hi = xv[2 * k + 1];
        xv[2 * k]     = cf[k] * lo + sf[k] * hi;
        xv[2 * k + 1] = cf[k] * hi - sf[k] * lo;
    }
}
__device__ __forceinline__ void rot4(F2 xv[8], const CS& C) {
    F2 cf[4] = {flo(C.c0), fhi(C.c0), flo(C.c1), fhi(C.c1)};
    F2 sf[4] = {flo(C.s0), fhi(C.s0), flo(C.s1), fhi(C.s1)};
#pragma unroll
    for (int k = 0; k < 2; ++k)
#pragma unroll
        for (int t = 0; t < 2; ++t) {
            F2 lo = xv[4 * k + t], hi = xv[4 * k + 2 + t];
            F2 c = cf[2 * k + t], s = sf[2 * k + t];
            xv[4 * k + t]     = c * lo + s * hi;
            xv[4 * k + 2 + t] = c * hi - s * lo;
        }
}
__device__ __forceinline__ void rot8(F2 xv[8], const CS& C) {
    F2 cf[4] = {flo(C.c0), fhi(C.c0), flo(C.c1), fhi(C.c1)};
    F2 sf[4] = {flo(C.s0), fhi(C.s0), flo(C.s1), fhi(C.s1)};
#pragma unroll
    for (int t = 0; t < 4; ++t) {
        F2 lo = xv[t], hi = xv[4 + t];
        xv[t]     = cf[t] * lo + sf[t] * hi;
        xv[4 + t] = cf[t] * hi - sf[t] * lo;
    }
}

struct Pre {               // prefetched per-module state (addresses + bias)
    int addr[16];
    float4 b0, b1;
};

__device__ __forceinline__ void load_pre(Pre& p, const int* __restrict__ indices,
                                         const float* __restrict__ biases,
                                         int m, int blk, int col) {
    const int4* ip = (const int4*)(indices + m * N_INW + blk * 16);
    int idx[16];
#pragma unroll
    for (int q = 0; q < 4; ++q) {
        int4 v = ip[q];
        idx[4 * q] = v.x; idx[4 * q + 1] = v.y;
        idx[4 * q + 2] = v.z; idx[4 * q + 3] = v.w;
    }
#pragma unroll
    for (int j = 0; j < 16; ++j) p.addr[j] = lds_addr(idx[j], col);
    const float4* bp = (const float4*)(biases + m * N_GROW + blk * 8);
    p.b0 = bp[0]; p.b1 = bp[1];
}

// ---- one butterfly module, M compile-time, fully straight-line ----
template <int M, bool USE_TABLE>
__device__ __forceinline__ void run_module(float* __restrict__ lds,
        const float* __restrict__ cs_tab, const float* __restrict__ angles,
        const float* __restrict__ biases, const int* __restrict__ indices,
        float* __restrict__ out, int blk, int col, int cg, Pre& st) {
    // gather 16 rows from LDS (addresses prefetched in previous module)
    float xg[16];
#pragma unroll
    for (int j = 0; j < 16; ++j)
        xg[j] = *(const float*)((const char*)lds + st.addr[j]);

    // IN-phase cs loads (consumers are after the barrier -> latency hidden)
    CS i0 = load_cs<USE_TABLE>(cs_tab, angles, 8 * M + 0, blk);
    CS i1 = load_cs<USE_TABLE>(cs_tab, angles, 8 * M + 1, blk);
    CS i2 = load_cs<USE_TABLE>(cs_tab, angles, 8 * M + 2, blk);
    CS i3 = load_cs<USE_TABLE>(cs_tab, angles, 8 * M + 3, blk);

    F2 xv[8];
#pragma unroll
    for (int k = 0; k < 8; ++k) xv[k] = f2mk(xg[2 * k], xg[2 * k + 1]);
    __syncthreads();            // all gathers complete before anyone scatters

    rot1(xv, i0); rot2(xv, i1); rot4(xv, i2); rot8(xv, i3);

    // OUT-phase cs loads (consumed after act/append/prefetch -> hidden)
    CS o0, o1, o2, o3;
    if (M < N_DEPTH - 1) {
        o0 = load_cs<USE_TABLE>(cs_tab, angles, 8 * M + 4, blk);
        o1 = load_cs<USE_TABLE>(cs_tab, angles, 8 * M + 5, blk);
        o2 = load_cs<USE_TABLE>(cs_tab, angles, 8 * M + 6, blk);
        o3 = load_cs<USE_TABLE>(cs_tab, angles, 8 * M + 7, blk);
    }

    // activation on rows 0..7 (= xv[0..3])
    F2 bf[4] = {flo(st.b0), fhi(st.b0), flo(st.b1), fhi(st.b1)};
    F2 av[4];
#pragma unroll
    for (int k = 0; k < 4; ++k) {
        F2 pre = xv[k] + bf[k];
        F2 t = pre * pre + 1.0f;
        F2 r = f2mk(__builtin_amdgcn_sqrtf(t.x), __builtin_amdgcn_sqrtf(t.y));
        F2 a = 0.5f * (pre + r);
        av[k] = a; xv[k] = a;
    }
    float af[8] = {av[0].x, av[0].y, av[1].x, av[1].y,
                   av[2].x, av[2].y, av[3].x, av[3].y};

    if (M < N_DEPTH - 1) {
        // append act rows base..base+7 in NATURAL order; swizzle class
        // (base>>3)+blk varies per blk -> banks spread, <=2-way (free).
        const int base  = N_INW + M * N_GROW + blk * 8;
        const int abyte = base * 16 + ((col + (base >> 3)) & 3) * 4;
#pragma unroll
        for (int j = 0; j < 8; ++j)
            *(float*)((char*)lds + (abyte + 16 * j)) = af[j];

        // prefetch next module's gather addresses + bias (used after barrier)
        Pre nx;
        load_pre(nx, indices, biases, M + 1, blk, col);

        rot1(xv, o0); rot2(xv, o1); rot4(xv, o2); rot8(xv, o3);

        float sc[16] = {xv[0].x, xv[0].y, xv[1].x, xv[1].y, xv[2].x, xv[2].y,
                        xv[3].x, xv[3].y, xv[4].x, xv[4].y, xv[5].x, xv[5].y,
                        xv[6].x, xv[6].y, xv[7].x, xv[7].y};
#pragma unroll
        for (int j = 0; j < 16; ++j)
            *(float*)((char*)lds + st.addr[j]) = sc[j];
        __syncthreads();        // scatters done before next module's gathers

        st = nx;
    } else {
        // module 7: OUT rotations + scatter are dead code w.r.t. the output.
#pragma unroll
        for (int j = 0; j < 8; ++j)
            out[(size_t)(blk * 8 + j) * N_BATCH + cg] = af[j];
    }
}

template <bool USE_TABLE>
__global__ __launch_bounds__(N_THREADS, 2)
void butterfly_fused_kernel(const float* __restrict__ input,
                            const float* __restrict__ scales,
                            const float* __restrict__ biases,
                            const int*   __restrict__ indices,
                            const float* __restrict__ cs_tab,
                            const float* __restrict__ angles,
                            float* __restrict__ out) {
    extern __shared__ float lds[];
    const int t   = threadIdx.x;
    const int blk = t >> 2;
    const int col = t & 3;
    // XCD swizzle: blockIdx%8 == x owns columns [x*512,(x+1)*512) so each 64B
    // input/output line is consumed within one XCD's L2.
    const int b   = blockIdx.x;
    const int cg  = (((b & 7) * 128) + (b >> 3)) * N_COL + col;

    Pre st;
    load_pre(st, indices, biases, 0, blk, col);

    // init: rows 0..1023 = scales[r] * input[r][cg]
#pragma unroll
    for (int k = 0; k < 16; ++k) {
        const int r = k * 64 + blk;
        *(float*)((char*)lds + lds_addr(r, col)) = scales[r] * input[(size_t)r * N_BATCH + cg];
    }
    __syncthreads();

    run_module<0, USE_TABLE>(lds, cs_tab, angles, biases, indices, out, blk, col, cg, st);
    run_module<1, USE_TABLE>(lds, cs_tab, angles, biases, indices, out, blk, col, cg, st);
    run_module<2, USE_TABLE>(lds, cs_tab, angles, biases, indices, out, blk, col, cg, st);
    run_module<3, USE_TABLE>(lds, cs_tab, angles, biases, indices, out, blk, col, cg, st);
    run_module<4, USE_TABLE>(lds, cs_tab, angles, biases, indices, out, blk, col, cg, st);
    run_module<5, USE_TABLE>(lds, cs_tab, angles, biases, indices, out, blk, col, cg, st);
    run_module<6, USE_TABLE>(lds, cs_tab, angles, biases, indices, out, blk, col, cg, st);
    run_module<7, USE_TABLE>(lds, cs_tab, angles, biases, indices, out, blk, col, cg, st);
}

// ---------------- host ----------------
extern "C" void kernel_launch(void* const* d_in, const int* in_sizes, int n_in,
                              void* d_out, int out_size, void* d_ws, size_t ws_size,
                              hipStream_t stream) {
    const float* input   = (const float*)d_in[0];
    const float* scales  = (const float*)d_in[1];
    const float* angles  = (const float*)d_in[2];
    const float* biases  = (const float*)d_in[3];
    const int*   indices = (const int*)d_in[4];
    float* out = (float*)d_out;

    const size_t cs_bytes  = (size_t)N_LAYERS * 2 * 512 * sizeof(float);  // 256 KB
    const size_t lds_bytes = (size_t)N_ROWS * N_COL * sizeof(float);      // 73728 B
    const int grid = N_BATCH / N_COL;                                     // 1024 WGs

    if (ws_size >= cs_bytes) {
        precompute_cs_kernel<<<N_LAYERS * 512 / 256, 256, 0, stream>>>(angles, (float*)d_ws);
        butterfly_fused_kernel<true><<<grid, N_THREADS, lds_bytes, stream>>>(
            input, scales, biases, indices, (const float*)d_ws, angles, out);
    } else {
        butterfly_fused_kernel<false><<<grid, N_THREADS, lds_bytes, stream>>>(
            input, scales, biases, indices, nullptr, angles, out);
    }
}

// Round 7
// 122.081 us; speedup vs baseline: 1.0260x; 1.0260x over previous
//
#include <hip/hip_runtime.h>
#include <math.h>

#define N_INW     1024
#define N_DEPTH   8
#define N_GROW    512
#define N_BATCH   4096
#define N_COL     4      // batch columns per workgroup
#define N_THREADS 256    // 64 butterfly blocks * 4 cols
#define N_LAYERS  64

// cs table planes: layer g: cos plane at [(2g)*512 + p], sin plane at [(2g+1)*512 + p]
__global__ void precompute_cs_kernel(const float* __restrict__ angles,
                                     float* __restrict__ cs) {
    int i = blockIdx.x * blockDim.x + threadIdx.x;
    if (i < N_LAYERS * 512) {
        int g = i >> 9, p = i & 511;
        float a = angles[i];
        cs[(2 * g) * 512 + p]     = cosf(a);
        cs[(2 * g + 1) * 512 + p] = sinf(a);
    }
}

// Padded LDS layout: float element index = r*4 + (r>>3) + c  (1 pad elem / 8 rows).
// Total: 4608 rows -> 576 groups * 33 elems = 19008 floats = 76032 B (incl. cols).
__device__ __forceinline__ int lads(int r, int c) {
    return r * 16 + ((r >> 3) << 2) + (c << 2);
}

#define LD(A)    (*(const float*)(L + (A)))
#define ST(A, V) do { *(float*)(L + (A)) = (V); } while (0)

// load cos/sin for table layer g into four named float4s (c[0..7], s[0..7])
#define LDCS(g, CA, CB, SA, SB) do { if (USE_TABLE) {                          \
    const float4* _c = (const float4*)(cs_tab + (2*(g))*512 + (blk<<3));       \
    const float4* _s = (const float4*)(cs_tab + (2*(g)+1)*512 + (blk<<3));     \
    CA = _c[0]; CB = _c[1]; SA = _s[0]; SB = _s[1];                            \
  } else {                                                                     \
    const float4* _p = (const float4*)(angles + (g)*512 + (blk<<3));           \
    float4 _a = _p[0], _b = _p[1];                                             \
    __sincosf(_a.x, &SA.x, &CA.x); __sincosf(_a.y, &SA.y, &CA.y);              \
    __sincosf(_a.z, &SA.z, &CA.z); __sincosf(_a.w, &SA.w, &CA.w);              \
    __sincosf(_b.x, &SB.x, &CB.x); __sincosf(_b.y, &SB.y, &CB.y);              \
    __sincosf(_b.z, &SB.z, &CB.z); __sincosf(_b.w, &SB.w, &CB.w);              \
  } } while (0)

#define ROTP(LO, HI, CC, SS) do { float _l = LO, _h = HI;                      \
    LO = CC * _l + SS * _h; HI = CC * _h - SS * _l; } while (0)

// stride-1: pairs (2k,2k+1), la=k
#define ROTS1(CA,CB,SA,SB) do {                                                \
    ROTP(x0,x1,CA.x,SA.x);  ROTP(x2,x3,CA.y,SA.y);                             \
    ROTP(x4,x5,CA.z,SA.z);  ROTP(x6,x7,CA.w,SA.w);                             \
    ROTP(x8,x9,CB.x,SB.x);  ROTP(x10,x11,CB.y,SB.y);                           \
    ROTP(x12,x13,CB.z,SB.z);ROTP(x14,x15,CB.w,SB.w); } while (0)
// stride-2: pairs (j,j+2), j in {0,1,4,5,8,9,12,13}, la=(j/4)*2+j%2
#define ROTS2(CA,CB,SA,SB) do {                                                \
    ROTP(x0,x2,CA.x,SA.x);  ROTP(x1,x3,CA.y,SA.y);                             \
    ROTP(x4,x6,CA.z,SA.z);  ROTP(x5,x7,CA.w,SA.w);                             \
    ROTP(x8,x10,CB.x,SB.x); ROTP(x9,x11,CB.y,SB.y);                            \
    ROTP(x12,x14,CB.z,SB.z);ROTP(x13,x15,CB.w,SB.w); } while (0)
// stride-4: pairs (j,j+4), j in {0..3,8..11}, la=(j/8)*4+j%4
#define ROTS4(CA,CB,SA,SB) do {                                                \
    ROTP(x0,x4,CA.x,SA.x);  ROTP(x1,x5,CA.y,SA.y);                             \
    ROTP(x2,x6,CA.z,SA.z);  ROTP(x3,x7,CA.w,SA.w);                             \
    ROTP(x8,x12,CB.x,SB.x); ROTP(x9,x13,CB.y,SB.y);                            \
    ROTP(x10,x14,CB.z,SB.z);ROTP(x11,x15,CB.w,SB.w); } while (0)
// stride-8: pairs (j,j+8), la=j
#define ROTS8(CA,CB,SA,SB) do {                                                \
    ROTP(x0,x8,CA.x,SA.x);  ROTP(x1,x9,CA.y,SA.y);                             \
    ROTP(x2,x10,CA.z,SA.z); ROTP(x3,x11,CA.w,SA.w);                            \
    ROTP(x4,x12,CB.x,SB.x); ROTP(x5,x13,CB.y,SB.y);                            \
    ROTP(x6,x14,CB.z,SB.z); ROTP(x7,x15,CB.w,SB.w); } while (0)

#define ACT1(X, BB) do { float _p = (X) + (BB);                                \
    X = 0.5f * (_p + __builtin_amdgcn_sqrtf(_p * _p + 1.0f)); } while (0)

// One butterfly module. M is a literal. All state in NAMED scalars (no arrays
// anywhere -> nothing can be demoted to scratch). Three rotating CS sets give
// ~1-layer load-ahead inside each phase; only x/addrs/i0-i3 cross barriers.
#define MODULE(M) {                                                            \
  const int a0=lads(i0.x,col), a1=lads(i0.y,col), a2=lads(i0.z,col),           \
            a3=lads(i0.w,col), a4=lads(i1.x,col), a5=lads(i1.y,col),           \
            a6=lads(i1.z,col), a7=lads(i1.w,col), a8=lads(i2.x,col),           \
            a9=lads(i2.y,col), a10=lads(i2.z,col), a11=lads(i2.w,col),         \
            a12=lads(i3.x,col), a13=lads(i3.y,col), a14=lads(i3.z,col),        \
            a15=lads(i3.w,col);                                                \
  float4 cA,cB,sA,sB, dA,dB,tA,tB, eA,eB,uA,uB, ba,bb;                         \
  LDCS(8*(M)+0, cA,cB,sA,sB);                                                  \
  LDCS(8*(M)+1, dA,dB,tA,tB);                                                  \
  float x0=LD(a0), x1=LD(a1), x2=LD(a2), x3=LD(a3);                            \
  float x4=LD(a4), x5=LD(a5), x6=LD(a6), x7=LD(a7);                            \
  float x8=LD(a8), x9=LD(a9), x10=LD(a10), x11=LD(a11);                        \
  float x12=LD(a12), x13=LD(a13), x14=LD(a14), x15=LD(a15);                    \
  if ((M) < 7) __syncthreads();   /* gathers done before anyone scatters */    \
  LDCS(8*(M)+2, eA,eB,uA,uB);                                                  \
  { const float4* _bp = (const float4*)(biases + (M)*N_GROW + (blk<<3));       \
    ba = _bp[0]; bb = _bp[1]; }                                                \
  ROTS1(cA,cB,sA,sB);                                                          \
  LDCS(8*(M)+3, cA,cB,sA,sB);                                                  \
  ROTS2(dA,dB,tA,tB);                                                          \
  ROTS4(eA,eB,uA,uB);                                                          \
  ROTS8(cA,cB,sA,sB);                                                          \
  ACT1(x0,ba.x); ACT1(x1,ba.y); ACT1(x2,ba.z); ACT1(x3,ba.w);                  \
  ACT1(x4,bb.x); ACT1(x5,bb.y); ACT1(x6,bb.z); ACT1(x7,bb.w);                  \
  if ((M) < 7) {                                                               \
    /* append act rows; pad layout spreads banks by blk -> <=4-way */          \
    const int _base = N_INW + (M)*N_GROW + (blk<<3);                           \
    const int _ab   = _base*16 + ((_base>>3)<<2) + (col<<2);                   \
    ST(_ab+ 0,x0); ST(_ab+16,x1); ST(_ab+32,x2); ST(_ab+ 48,x3);               \
    ST(_ab+64,x4); ST(_ab+80,x5); ST(_ab+96,x6); ST(_ab+112,x7);               \
    /* prefetch next module's indices (named int4s, live across barrier) */    \
    { const int4* _ip = (const int4*)(indices + ((M)+1)*N_INW + (blk<<4));     \
      i0=_ip[0]; i1=_ip[1]; i2=_ip[2]; i3=_ip[3]; }                            \
    LDCS(8*(M)+4, dA,dB,tA,tB);                                                \
    LDCS(8*(M)+5, eA,eB,uA,uB);                                                \
    ROTS1(dA,dB,tA,tB);                                                        \
    LDCS(8*(M)+6, dA,dB,tA,tB);                                                \
    ROTS2(eA,eB,uA,uB);                                                        \
    LDCS(8*(M)+7, eA,eB,uA,uB);                                                \
    ROTS4(dA,dB,tA,tB);                                                        \
    ROTS8(eA,eB,uA,uB);                                                        \
    ST(a0,x0);  ST(a1,x1);  ST(a2,x2);  ST(a3,x3);                             \
    ST(a4,x4);  ST(a5,x5);  ST(a6,x6);  ST(a7,x7);                             \
    ST(a8,x8);  ST(a9,x9);  ST(a10,x10); ST(a11,x11);                          \
    ST(a12,x12); ST(a13,x13); ST(a14,x14); ST(a15,x15);                        \
    __syncthreads();            /* scatters done before next gathers */        \
  } else {                                                                     \
    /* module 7: OUT rotations + scatter are dead code w.r.t. the output */    \
    out[(size_t)((blk<<3)+0)*N_BATCH+cg]=x0;                                   \
    out[(size_t)((blk<<3)+1)*N_BATCH+cg]=x1;                                   \
    out[(size_t)((blk<<3)+2)*N_BATCH+cg]=x2;                                   \
    out[(size_t)((blk<<3)+3)*N_BATCH+cg]=x3;                                   \
    out[(size_t)((blk<<3)+4)*N_BATCH+cg]=x4;                                   \
    out[(size_t)((blk<<3)+5)*N_BATCH+cg]=x5;                                   \
    out[(size_t)((blk<<3)+6)*N_BATCH+cg]=x6;                                   \
    out[(size_t)((blk<<3)+7)*N_BATCH+cg]=x7;                                   \
  } }

template <bool USE_TABLE>
__global__ __launch_bounds__(N_THREADS, 2)
void butterfly_fused_kernel(const float* __restrict__ input,
                            const float* __restrict__ scales,
                            const float* __restrict__ biases,
                            const int*   __restrict__ indices,
                            const float* __restrict__ cs_tab,
                            const float* __restrict__ angles,
                            float* __restrict__ out) {
    extern __shared__ float ldsbuf[];
    char* L = (char*)ldsbuf;
    const int t   = threadIdx.x;
    const int blk = t >> 2;
    const int col = t & 3;
    // XCD swizzle: blockIdx%8 == x owns columns [x*512,(x+1)*512) so each 64B
    // input/output line is consumed within one XCD's L2.
    const int b   = blockIdx.x;
    const int cg  = (((b & 7) * 128) + (b >> 3)) * N_COL + col;

    int4 i0, i1, i2, i3;
    { const int4* ip = (const int4*)(indices + (blk << 4));
      i0 = ip[0]; i1 = ip[1]; i2 = ip[2]; i3 = ip[3]; }

    // init: rows 0..1023 = scales[r] * input[r][cg]
#pragma unroll
    for (int k = 0; k < 16; ++k) {
        const int r = (k << 6) + blk;
        *(float*)(L + lads(r, col)) = scales[r] * input[(size_t)r * N_BATCH + cg];
    }
    __syncthreads();

    MODULE(0) MODULE(1) MODULE(2) MODULE(3)
    MODULE(4) MODULE(5) MODULE(6) MODULE(7)
}

// ---------------- host ----------------
extern "C" void kernel_launch(void* const* d_in, const int* in_sizes, int n_in,
                              void* d_out, int out_size, void* d_ws, size_t ws_size,
                              hipStream_t stream) {
    const float* input   = (const float*)d_in[0];
    const float* scales  = (const float*)d_in[1];
    const float* angles  = (const float*)d_in[2];
    const float* biases  = (const float*)d_in[3];
    const int*   indices = (const int*)d_in[4];
    float* out = (float*)d_out;

    const size_t cs_bytes  = (size_t)N_LAYERS * 2 * 512 * sizeof(float); // 256 KB
    // 4608 rows -> 576 groups * 33 elems (cols already included) = 19008 floats
    const size_t lds_bytes = (size_t)576 * 33 * sizeof(float);           // 76032 B
    const int grid = N_BATCH / N_COL;                                    // 1024 WGs

    if (ws_size >= cs_bytes) {
        precompute_cs_kernel<<<N_LAYERS * 512 / 256, 256, 0, stream>>>(angles, (float*)d_ws);
        butterfly_fused_kernel<true><<<grid, N_THREADS, lds_bytes, stream>>>(
            input, scales, biases, indices, (const float*)d_ws, angles, out);
    } else {
        butterfly_fused_kernel<false><<<grid, N_THREADS, lds_bytes, stream>>>(
            input, scales, biases, indices, nullptr, angles, out);
    }
}